// Round 11
// baseline (285.678 us; speedup 1.0000x reference)
//
#include <hip/hip_runtime.h>
#include <math.h>

#define NN 50000
#define EE 1600000
#define IN_DIM 256
#define H_DIM 64
#define C_DIM 16
#define NT 5000
#define NBUK 391  // ceil(NN/128)
#define CHUNK 2048
#define NCHUNK 782  // ceil(EE/CHUNK): 781*2048=1599488, last block 512
#define PAD 6144   // per-bucket capacity
#define CAP 6144

typedef short bf16x8 __attribute__((ext_vector_type(8)));
typedef float f32x4 __attribute__((ext_vector_type(4)));

__device__ __forceinline__ unsigned short f2bf(float f) {
    unsigned int u = __float_as_uint(f);
    u = (u + 0x7FFFu + ((u >> 16) & 1u)) >> 16;  // RNE
    return (unsigned short)u;
}
__device__ __forceinline__ void acc_dw(float2& a, unsigned u) {
    float2 t;
    t.x = __uint_as_float(u << 16);
    t.y = __uint_as_float(u & 0xFFFF0000u);
    a.x += t.x;
    a.y += t.y;
}
__device__ __forceinline__ void acc_u4(float2* acc, uint4 v) {
    acc_dw(acc[0], v.x); acc_dw(acc[1], v.y); acc_dw(acc[2], v.z); acc_dw(acc[3], v.w);
}

// ---------------- init: cursors, bf16-transposed weights ----------------
__global__ __launch_bounds__(256) void init_kernel(const float* __restrict__ W1, const float* __restrict__ W2,
                                                   unsigned short* __restrict__ WT1, unsigned short* __restrict__ WT2,
                                                   int* __restrict__ cursor) {
    int i = blockIdx.x * 256 + threadIdx.x;
    if (i < NBUK) cursor[i] = i * PAD;
    if (i < 64 * 256) {
        int n = i >> 8, k = i & 255;
        WT1[i] = f2bf(W1[k * 64 + n]);
    }
    int j = i - 64 * 256;
    if (j >= 0 && j < 2 * 64 * 64) {
        int l = j >> 12, r = j & 4095;
        int n = r >> 6, k = r & 63;
        WT2[j] = f2bf(W2[l * 4096 + k * 64 + n]);
    }
}

// ---------------- multisplit into padded per-bucket regions (782 blocks for occupancy) ----------------
// stag packs (b<<23)|(dlow<<16)|src -- 9+7+16 = 32 bits (src < 65536).
__global__ __launch_bounds__(256) void multisplit_kernel(const int* __restrict__ src, const int* __restrict__ dst,
                                                         int* __restrict__ cursor, unsigned int* __restrict__ temp) {
    __shared__ int hist[NBUK];
    __shared__ int excl[NBUK + 1];
    __shared__ int offs[NBUK];
    __shared__ int delta[NBUK];
    __shared__ unsigned int stag[CHUNK];

    const int tid = threadIdx.x;
    const int base_e = blockIdx.x * CHUNK;

    for (int i = tid; i < NBUK; i += 256) hist[i] = 0;
    __syncthreads();

    for (int i = tid; i < CHUNK; i += 256) {
        int e = base_e + i;
        if (e < EE) atomicAdd(&hist[dst[e] >> 7], 1);
    }
    __syncthreads();

    if (tid < 64) {
        int lane = tid;
        int lc[7];
        int s = 0;
#pragma unroll
        for (int k = 0; k < 7; ++k) {
            int idx = lane * 7 + k;
            int c = (idx < NBUK) ? hist[idx] : 0;
            lc[k] = c;
            s += c;
        }
        int v = s;
#pragma unroll
        for (int off = 1; off < 64; off <<= 1) {
            int u = __shfl_up(v, off);
            if (lane >= off) v += u;
        }
        int ex = v - s;
#pragma unroll
        for (int k = 0; k < 7; ++k) {
            int idx = lane * 7 + k;
            if (idx < NBUK) excl[idx] = ex;
            ex += lc[k];
        }
        if (lane == 63) excl[NBUK] = v;
    }
    __syncthreads();

    for (int b = tid; b < NBUK; b += 256) {
        int count = excl[b + 1] - excl[b];
        if (count) {
            int gbase = atomicAdd(&cursor[b], count);
            delta[b] = gbase - excl[b];
        }
        offs[b] = excl[b];
    }
    __syncthreads();

    for (int i = tid; i < CHUNK; i += 256) {
        int e = base_e + i;
        if (e < EE) {
            int d = dst[e];
            int s = src[e];
            int b = d >> 7;
            int rank = atomicAdd(&offs[b], 1);
            stag[rank] = ((unsigned)b << 23) | ((unsigned)(d & 127) << 16) | (unsigned)s;
        }
    }
    __syncthreads();

    int nval = excl[NBUK];
    for (int i = tid; i < nval; i += 256) {
        unsigned int v = stag[i];
        temp[delta[v >> 23] + i] = v & 0x7FFFFFu;
    }
}

// ---------------- per-bucket finalize (512 threads): counts (padded x8) -> row_beg/row_end + dinv, place col ----------------
__global__ __launch_bounds__(512) void bucket_finalize_kernel(const unsigned int* __restrict__ temp,
                                                              const int* __restrict__ cursor,
                                                              int* __restrict__ row_beg, int* __restrict__ row_end,
                                                              float* __restrict__ dinv, int* __restrict__ col) {
    __shared__ int cnt_l[128];
    __shared__ int exc[129];
    __shared__ int cur[128];
    __shared__ unsigned int stag[CAP];
    __shared__ int stag2[CAP];
    const int b = blockIdx.x;
    const int tid = threadIdx.x;
    const int d0 = b << 7;
    const int nd = (d0 + 128 < NN) ? 128 : (NN - d0);
    const int base = b * PAD;
    int M = cursor[b] - base;
    if (M > CAP) M = CAP;  // statistically unreachable

    if (tid < 128) cnt_l[tid] = 0;
    __syncthreads();

    for (int i = tid; i < M; i += 512) {
        unsigned int v = temp[base + i];
        stag[i] = v;
        atomicAdd(&cnt_l[(v >> 16) & 127], 1);
    }
    __syncthreads();

    // exclusive scan of PADDED counts (each row rounded up to multiple of 8)
    if (tid < 64) {
        int c0 = (cnt_l[2 * tid] + 7) & ~7;
        int c1 = (cnt_l[2 * tid + 1] + 7) & ~7;
        int s = c0 + c1;
        int v = s;
#pragma unroll
        for (int off = 1; off < 64; off <<= 1) {
            int u = __shfl_up(v, off);
            if (tid >= off) v += u;
        }
        int ex = v - s;
        exc[2 * tid] = ex;
        exc[2 * tid + 1] = ex + c0;
        if (tid == 63) exc[128] = v;  // == M_pad
    }
    __syncthreads();
    const int Mp = exc[128];

    if (tid < nd) {
        row_beg[d0 + tid] = base + exc[tid];
        row_end[d0 + tid] = base + exc[tid + 1];
        dinv[d0 + tid] = rsqrtf((float)(cnt_l[tid] + 1));  // +1 self-loop (real degree)
    }

    if (tid < 128) cur[tid] = exc[tid];
    for (int i = tid; i < Mp; i += 512) stag2[i] = NN;  // pad -> zero row
    __syncthreads();

    for (int i = tid; i < M; i += 512) {
        unsigned int v = stag[i];
        int r = atomicAdd(&cur[(v >> 16) & 127], 1);
        stag2[r] = (int)(v & 0xFFFFu);
    }
    __syncthreads();
    for (int i = tid; i < Mp; i += 512) col[base + i] = stag2[i];
}

// ---------------- GEMM layer 0: fp32 feats (LDS-staged, cvt) x WT1 (direct global B frags) ----------------
__global__ __launch_bounds__(256) void gemm0_mfma(const float* __restrict__ x, const unsigned short* __restrict__ WT,
                                                  const float* __restrict__ dinv, unsigned short* __restrict__ y) {
    __shared__ unsigned short As[64 * 72];
    const int tid = threadIdx.x;
    const int wv = tid >> 6, lane = tid & 63;
    const int mn = lane & 15, quad = lane >> 4;
    const int row0 = blockIdx.x * 64;

    f32x4 acc[4];
#pragma unroll
    for (int t = 0; t < 4; ++t) acc[t] = (f32x4){0.f, 0.f, 0.f, 0.f};

    for (int k0 = 0; k0 < 256; k0 += 64) {
        __syncthreads();
#pragma unroll
        for (int it = 0; it < 4; ++it) {
            int i = tid + 256 * it;
            int row = i >> 4, c4 = (i & 15) << 2;
            int gr = row0 + row;
            float4 v = make_float4(0.f, 0.f, 0.f, 0.f);
            if (gr < NN) v = *(const float4*)(x + (size_t)gr * 256 + k0 + c4);
            ushort4 o;
            o.x = f2bf(v.x); o.y = f2bf(v.y); o.z = f2bf(v.z); o.w = f2bf(v.w);
            *(ushort4*)&As[row * 72 + c4] = o;
        }
        __syncthreads();
#pragma unroll
        for (int kk = 0; kk < 2; ++kk) {
            bf16x8 a = *(const bf16x8*)&As[(wv * 16 + mn) * 72 + kk * 32 + quad * 8];
#pragma unroll
            for (int t = 0; t < 4; ++t) {
                bf16x8 bfr = *(const bf16x8*)(WT + (t * 16 + mn) * 256 + k0 + kk * 32 + quad * 8);
                acc[t] = __builtin_amdgcn_mfma_f32_16x16x32_bf16(a, bfr, acc[t], 0, 0, 0);
            }
        }
    }
    __syncthreads();
    float dv[4];
#pragma unroll
    for (int r = 0; r < 4; ++r) {
        int gr = row0 + wv * 16 + quad * 4 + r;
        dv[r] = (gr < NN) ? dinv[gr] : 0.f;
    }
#pragma unroll
    for (int t = 0; t < 4; ++t)
#pragma unroll
        for (int r = 0; r < 4; ++r)
            As[(wv * 16 + quad * 4 + r) * 72 + t * 16 + mn] = f2bf(acc[t][r] * dv[r]);
    __syncthreads();
#pragma unroll
    for (int it = 0; it < 2; ++it) {
        int i = tid + 256 * it;
        int row = i >> 3, c8 = (i & 7) << 3;
        int gr = row0 + row;
        if (gr < NN) *(uint4*)(y + (size_t)gr * 64 + c8) = *(uint4*)&As[row * 72 + c8];
    }
    if (blockIdx.x == 0 && tid < 8) {
        uint4 z = {0u, 0u, 0u, 0u};
        *(uint4*)(y + (size_t)NN * 64 + tid * 8) = z;
    }
}

// ---------------- GEMM hidden: bf16 A direct global, bf16 WT direct global, LDS only for epilogue ----------------
__global__ __launch_bounds__(256) void gemmH_mfma(const unsigned short* __restrict__ xb,
                                                  const unsigned short* __restrict__ WT,
                                                  const float* __restrict__ dinv, unsigned short* __restrict__ y) {
    __shared__ unsigned short As[64 * 72];
    const int tid = threadIdx.x;
    const int wv = tid >> 6, lane = tid & 63;
    const int mn = lane & 15, quad = lane >> 4;
    const int row0 = blockIdx.x * 64;
    const unsigned arow = (unsigned)(row0 + wv * 16 + mn);

    f32x4 acc[4];
#pragma unroll
    for (int t = 0; t < 4; ++t) acc[t] = (f32x4){0.f, 0.f, 0.f, 0.f};

#pragma unroll
    for (int kk = 0; kk < 2; ++kk) {
        bf16x8 a = *(const bf16x8*)(xb + (arow << 6) + kk * 32 + quad * 8);
#pragma unroll
        for (int t = 0; t < 4; ++t) {
            bf16x8 bfr = *(const bf16x8*)(WT + ((t * 16 + mn) << 6) + kk * 32 + quad * 8);
            acc[t] = __builtin_amdgcn_mfma_f32_16x16x32_bf16(a, bfr, acc[t], 0, 0, 0);
        }
    }
    float dv[4];
#pragma unroll
    for (int r = 0; r < 4; ++r) {
        int gr = row0 + wv * 16 + quad * 4 + r;
        dv[r] = (gr < NN) ? dinv[gr] : 0.f;
    }
#pragma unroll
    for (int t = 0; t < 4; ++t)
#pragma unroll
        for (int r = 0; r < 4; ++r)
            As[(wv * 16 + quad * 4 + r) * 72 + t * 16 + mn] = f2bf(acc[t][r] * dv[r]);
    __syncthreads();
#pragma unroll
    for (int it = 0; it < 2; ++it) {
        int i = tid + 256 * it;
        int row = i >> 3, c8 = (i & 7) << 3;
        int gr = row0 + row;
        if (gr < NN) *(uint4*)(y + (size_t)gr * 64 + c8) = *(uint4*)&As[row * 72 + c8];
    }
    if (blockIdx.x == 0 && tid < 8) {
        uint4 z = {0u, 0u, 0u, 0u};
        *(uint4*)(y + (size_t)NN * 64 + tid * 8) = z;
    }
}

// ---------------- Aggregate core: wave = 1 dst; 8 slots x 8 lanes; lane = uint4 (8 bf16) ----------------
__device__ __forceinline__ void agg_core8(const unsigned short* __restrict__ y, const int* __restrict__ col,
                                          int d, int s0, int s1, int g, int h0, float dv,
                                          const float* __restrict__ b, float* __restrict__ r) {
    float2 accA[4] = {{0.f, 0.f}, {0.f, 0.f}, {0.f, 0.f}, {0.f, 0.f}};
    float2 accB[4] = {{0.f, 0.f}, {0.f, 0.f}, {0.f, 0.f}, {0.f, 0.f}};
    if (g == 0) {
        uint4 v = *(const uint4*)(y + (((unsigned)d) << 6) + h0);
        acc_u4(accA, v);
    }
    int e = s0;
    int rem = s1 - s0;  // multiple of 8
    int a0, a1, a2, a3;
    if (rem >= 32) {
        a0 = col[e + g]; a1 = col[e + 8 + g]; a2 = col[e + 16 + g]; a3 = col[e + 24 + g];
    }
    while (rem >= 32) {
        uint4 v0 = *(const uint4*)(y + (((unsigned)a0) << 6) + h0);
        uint4 v1 = *(const uint4*)(y + (((unsigned)a1) << 6) + h0);
        uint4 v2 = *(const uint4*)(y + (((unsigned)a2) << 6) + h0);
        uint4 v3 = *(const uint4*)(y + (((unsigned)a3) << 6) + h0);
        e += 32; rem -= 32;
        int n0, n1, n2, n3;
        if (rem >= 32) {
            n0 = col[e + g]; n1 = col[e + 8 + g]; n2 = col[e + 16 + g]; n3 = col[e + 24 + g];
        }
        acc_u4(accA, v0); acc_u4(accB, v1); acc_u4(accA, v2); acc_u4(accB, v3);
        if (rem >= 32) { a0 = n0; a1 = n1; a2 = n2; a3 = n3; }
    }
    if (rem) {
        int c0 = col[e + g];
        int c1 = (rem > 8) ? col[e + 8 + g] : 0;
        int c2 = (rem > 16) ? col[e + 16 + g] : 0;
        uint4 v0 = *(const uint4*)(y + (((unsigned)c0) << 6) + h0);
        acc_u4(accA, v0);
        if (rem > 8) {
            uint4 v1 = *(const uint4*)(y + (((unsigned)c1) << 6) + h0);
            acc_u4(accB, v1);
        }
        if (rem > 16) {
            uint4 v2 = *(const uint4*)(y + (((unsigned)c2) << 6) + h0);
            acc_u4(accA, v2);
        }
    }
#pragma unroll
    for (int j = 0; j < 4; ++j) {
        float sx = accA[j].x + accB[j].x;
        float sy = accA[j].y + accB[j].y;
        sx += __shfl_xor(sx, 8); sx += __shfl_xor(sx, 16); sx += __shfl_xor(sx, 32);
        sy += __shfl_xor(sy, 8); sy += __shfl_xor(sy, 16); sy += __shfl_xor(sy, 32);
        r[2 * j] = dv * sx + b[h0 + 2 * j];
        r[2 * j + 1] = dv * sy + b[h0 + 2 * j + 1];
    }
}

__global__ __launch_bounds__(256) void aggregate_kernel(const unsigned short* __restrict__ y,
                                                        const int* __restrict__ row_beg, const int* __restrict__ row_end,
                                                        const int* __restrict__ col, const float* __restrict__ dinv,
                                                        const float* __restrict__ b, unsigned short* __restrict__ xout,
                                                        int relu) {
    const int tid = threadIdx.x;
    const int wv = tid >> 6, lane = tid & 63;
    const int g = lane >> 3, l = lane & 7;
    const int h0 = l << 3;
    const int d = blockIdx.x * 4 + wv;
    const int s0 = row_beg[d], s1 = row_end[d];
    float r[8];
    agg_core8(y, col, d, s0, s1, g, h0, dinv[d], b, r);
    if (relu) {
#pragma unroll
        for (int j = 0; j < 8; ++j) r[j] = fmaxf(r[j], 0.f);
    }
    if (g == 0) {
        uint4 o;
        o.x = (unsigned)f2bf(r[0]) | ((unsigned)f2bf(r[1]) << 16);
        o.y = (unsigned)f2bf(r[2]) | ((unsigned)f2bf(r[3]) << 16);
        o.z = (unsigned)f2bf(r[4]) | ((unsigned)f2bf(r[5]) << 16);
        o.w = (unsigned)f2bf(r[6]) | ((unsigned)f2bf(r[7]) << 16);
        *(uint4*)(xout + (((unsigned)d) << 6) + h0) = o;
    }
}

// Layer-2 aggregate fused with relu -> L2 normalize -> write h -> logits -> log_softmax -> pred
__global__ __launch_bounds__(256) void aggregate_final_kernel(const unsigned short* __restrict__ y,
                                                              const int* __restrict__ row_beg, const int* __restrict__ row_end,
                                                              const int* __restrict__ col, const float* __restrict__ dinv,
                                                              const float* __restrict__ b,
                                                              const float* __restrict__ W3, const float* __restrict__ b3,
                                                              float* __restrict__ out) {
    const int tid = threadIdx.x;
    const int wv = tid >> 6, lane = tid & 63;
    const int g = lane >> 3, l = lane & 7;
    const int h0 = l << 3;
    const int d = blockIdx.x * 4 + wv;
    const int s0 = row_beg[d], s1 = row_end[d];
    float r[8];
    agg_core8(y, col, d, s0, s1, g, h0, dinv[d], b, r);
#pragma unroll
    for (int j = 0; j < 8; ++j) r[j] = fmaxf(r[j], 0.f);

    float sq = 0.f;
#pragma unroll
    for (int j = 0; j < 8; ++j) sq += r[j] * r[j];
    sq += __shfl_xor(sq, 1);
    sq += __shfl_xor(sq, 2);
    sq += __shfl_xor(sq, 4);
    float inv = 1.0f / fmaxf(sqrtf(sq), 1e-12f);

    __shared__ float hl[4][68];
    if (g == 0) {
        float4 hA = make_float4(r[0] * inv, r[1] * inv, r[2] * inv, r[3] * inv);
        float4 hB = make_float4(r[4] * inv, r[5] * inv, r[6] * inv, r[7] * inv);
        float* op = out + 1 + (size_t)NN * C_DIM + (size_t)d * 64 + h0;
        *(float4*)op = hA;
        *(float4*)(op + 4) = hB;
        *(float4*)&hl[wv][h0] = hA;
        *(float4*)&hl[wv][h0 + 4] = hB;
    }
    __syncthreads();

    int c = lane & 15, chunk = lane >> 4;
    float part = 0.f;
#pragma unroll
    for (int q = 0; q < 16; ++q) {
        int hh = chunk * 16 + q;
        part += hl[wv][hh] * W3[hh * 16 + c];
    }
    part += __shfl_xor(part, 16);
    part += __shfl_xor(part, 32);
    float logit = part + b3[c];

    float m = logit;
#pragma unroll
    for (int off = 8; off > 0; off >>= 1) m = fmaxf(m, __shfl_xor(m, off));
    float ex = __expf(logit - m);
    float se = ex;
#pragma unroll
    for (int off = 8; off > 0; off >>= 1) se += __shfl_xor(se, off);
    float pred = logit - m - __logf(se);
    if (lane < 16) out[1 + (size_t)d * 16 + lane] = pred;
}

// ---------------- loss: single block, fused mean ----------------
__global__ __launch_bounds__(1024) void loss_kernel(const float* __restrict__ out, const int* __restrict__ labels,
                                                    const int* __restrict__ train_idx, float* __restrict__ outw) {
    const int tid = threadIdx.x;
    float v = 0.f;
    for (int i = tid; i < NT; i += 1024) {
        int idx = train_idx[i];
        int lab = labels[idx];
        v -= out[1 + (size_t)idx * 16 + lab];
    }
#pragma unroll
    for (int off = 32; off > 0; off >>= 1) v += __shfl_xor(v, off);
    __shared__ float ws16[16];
    int wv = tid >> 6, lane = tid & 63;
    if (lane == 0) ws16[wv] = v;
    __syncthreads();
    if (tid == 0) {
        float s = 0.f;
#pragma unroll
        for (int k = 0; k < 16; ++k) s += ws16[k];
        outw[0] = s * (1.0f / NT);
    }
}

// ---------------- launch ----------------

extern "C" void kernel_launch(void* const* d_in, const int* in_sizes, int n_in,
                              void* d_out, int out_size, void* d_ws, size_t ws_size,
                              hipStream_t stream) {
    const float* feats = (const float*)d_in[0];
    const float* W1 = (const float*)d_in[1];
    const float* b1 = (const float*)d_in[2];
    const float* W2 = (const float*)d_in[3];
    const float* b2 = (const float*)d_in[4];
    const float* W3 = (const float*)d_in[5];
    const float* b3 = (const float*)d_in[6];
    const int* edge_list = (const int*)d_in[7];
    const int* labels = (const int*)d_in[8];
    const int* train_idx = (const int*)d_in[9];
    float* out = (float*)d_out;

    char* w = (char*)d_ws;
    auto alloc = [&](size_t bytes) {
        char* p = w;
        w += (bytes + 255) & ~(size_t)255;
        return p;
    };
    int* row_beg = (int*)alloc((size_t)NN * 4);
    int* row_end = (int*)alloc((size_t)NN * 4);
    int* col = (int*)alloc((size_t)NBUK * PAD * 4);
    unsigned int* temp = (unsigned int*)alloc((size_t)NBUK * PAD * 4);
    float* dinv = (float*)alloc((size_t)NN * 4);
    unsigned short* yb = (unsigned short*)alloc((size_t)(NN + 64) * 64 * 2);
    unsigned short* xb = (unsigned short*)alloc((size_t)(NN + 64) * 64 * 2);
    unsigned short* WT1 = (unsigned short*)alloc((size_t)64 * 256 * 2);
    unsigned short* WT2 = (unsigned short*)alloc((size_t)2 * 64 * 64 * 2);
    int* cursor = (int*)alloc((size_t)NBUK * 4);

    const int* srcp = edge_list;
    const int* dstp = edge_list + EE;

    init_kernel<<<96, 256, 0, stream>>>(W1, W2, WT1, WT2, cursor);
    multisplit_kernel<<<NCHUNK, 256, 0, stream>>>(srcp, dstp, cursor, temp);
    bucket_finalize_kernel<<<NBUK, 512, 0, stream>>>(temp, cursor, row_beg, row_end, dinv, col);

    const int GB = (NN + 63) / 64;  // 782
    // layer 0
    gemm0_mfma<<<GB, 256, 0, stream>>>(feats, WT1, dinv, yb);
    aggregate_kernel<<<NN / 4, 256, 0, stream>>>(yb, row_beg, row_end, col, dinv, b1, xb, 0);
    // layer 1
    gemmH_mfma<<<GB, 256, 0, stream>>>(xb, WT2, dinv, yb);
    aggregate_kernel<<<NN / 4, 256, 0, stream>>>(yb, row_beg, row_end, col, dinv, b2, xb, 1);
    // layer 2 + fused tail
    gemmH_mfma<<<GB, 256, 0, stream>>>(xb, WT2 + 4096, dinv, yb);
    aggregate_final_kernel<<<NN / 4, 256, 0, stream>>>(yb, row_beg, row_end, col, dinv, b2 + H_DIM, W3, b3, out);

    loss_kernel<<<1, 1024, 0, stream>>>(out, labels, train_idx, out);
}